// Round 7
// baseline (168.076 us; speedup 1.0000x reference)
//
#include <hip/hip_runtime.h>
#include <stdint.h>

// Problem constants (reference: B,T,D=4,4096,1024; E,C,O=8,1024,512)
#define Bdim 4
#define Tdim 4096
#define Ddim 1024
#define Edim 8
#define Cdim 1024
#define Odim 512
#define KT 16           // K tiles of 64 (Ddim/64)
#define PAN 16384       // ushorts per W K-panel: 256 rows * 64 elems

using bf16x8 = __attribute__((ext_vector_type(8))) __bf16;
using f32x4  = __attribute__((ext_vector_type(4))) float;
using u16x8  = __attribute__((ext_vector_type(8))) unsigned short;

// round-to-nearest-even f32 -> bf16
__device__ __forceinline__ unsigned short f2bf(float f) {
  unsigned int u = __float_as_uint(f);
  u += 0x7fffu + ((u >> 16) & 1u);
  return (unsigned short)(u >> 16);
}

// R11 prep, ONE dispatch:
//  [0, nx4):      linear x cast f32->bf16 (float4 -> ushort4), 96MB traffic
//  [nx4, nTot):   W'[e][nt][kt][256][64] bf16 panels, row r slot c holds
//                 global k-chunk (c ^ (r&7)) — XOR pre-swizzle baked so the
//                 GEMM B-DMA is contiguous 1KB/instr (R7-proven). 24MB.
__global__ void prep(const float* __restrict__ x,
                     const float* __restrict__ w,
                     unsigned short* __restrict__ xbf,
                     unsigned short* __restrict__ Wp,
                     int nx4, int nTot) {
  const int i = blockIdx.x * blockDim.x + threadIdx.x;
  if (i >= nTot) return;
  if (i < nx4) {
    float4 v = reinterpret_cast<const float4*>(x)[i];
    ushort4 o;
    o.x = f2bf(v.x); o.y = f2bf(v.y); o.z = f2bf(v.z); o.w = f2bf(v.w);
    reinterpret_cast<ushort4*>(xbf)[i] = o;
    return;
  }
  const int j  = i - nx4;
  const int c  = j & 7;
  const int r  = (j >> 3) & 255;
  const int kt = (j >> 11) & 15;
  const int nt = (j >> 15) & 1;
  const int e  = j >> 16;
  const float* src = w + ((size_t)(e * Odim + nt * 256 + r)) * Ddim + kt * 64 +
                     ((c ^ (r & 7)) * 8);
  const float4 v0 = reinterpret_cast<const float4*>(src)[0];
  const float4 v1 = reinterpret_cast<const float4*>(src)[1];
  u16x8 o;
  o[0] = f2bf(v0.x); o[1] = f2bf(v0.y); o[2] = f2bf(v0.z); o[3] = f2bf(v0.w);
  o[4] = f2bf(v1.x); o[5] = f2bf(v1.y); o[6] = f2bf(v1.z); o[7] = f2bf(v1.w);
  *reinterpret_cast<u16x8*>(Wp + (size_t)j * 8) = o;
}

// async global->LDS, 16B per lane; LDS dest is wave-uniform base.
__device__ __forceinline__ void async_copy16(const unsigned short* g,
                                             unsigned short* l) {
  __builtin_amdgcn_global_load_lds(
      (__attribute__((address_space(1))) unsigned int*)g,
      (__attribute__((address_space(3))) unsigned int*)l, 16, 0, 0);
}

#define FENCE() asm volatile("" ::: "memory")
#define BAR()   do { FENCE(); __builtin_amdgcn_s_barrier(); FENCE(); } while (0)

// R11 GEMM = R7 schedule verbatim (256x256, 8 waves, 4 quadrant-phases per
// K-tile, counted vmcnt(6) — never 0 in main loop, T5 setprio, T2 swizzle,
// T1 XCD swizzle, 8 static LDS arrays, all staging via global_load_lds) with
// MIXED sources: A gathered-DMA from linear xbf (R6-style: swizzled per-lane
// source, 8 scattered 128B rows/instr — avoids the 64MB A-panel round-trip
// that made R7's relayout a 45us traffic loser), B contiguous-DMA from the
// small pre-swizzled W panels (R7-style, 1KB/instr). Fusion lineage (R8-R10)
// abandoned: the 128-AGPR accumulator leaves too few arch VGPRs to hide
// gather latency in-register (spill or 70us, measured).
__global__ __launch_bounds__(512) void moe_mfma_gemm(
    const unsigned short* __restrict__ xbf,   // (B,T,D) bf16 linear
    const unsigned short* __restrict__ Wpan,  // pre-swizzled W panels
    const int* __restrict__ idx,              // (B,E,C)
    const float* __restrict__ bias,           // (E,O)
    float* __restrict__ out) {                // (B,E,C,O) f32
  __shared__ __align__(16) unsigned short sA_e0[128 * 64];
  __shared__ __align__(16) unsigned short sA_e1[128 * 64];
  __shared__ __align__(16) unsigned short sA_o0[128 * 64];
  __shared__ __align__(16) unsigned short sA_o1[128 * 64];
  __shared__ __align__(16) unsigned short sB_e0[128 * 64];
  __shared__ __align__(16) unsigned short sB_e1[128 * 64];
  __shared__ __align__(16) unsigned short sB_o0[128 * 64];
  __shared__ __align__(16) unsigned short sB_o1[128 * 64];

  // XCD-aware decode: e fastest (XCD = e). 256 blocks = 1/CU.
  const int bid = blockIdx.x;
  const int e   = bid & 7;
  const int rr_ = bid >> 3;       // 0..31
  const int nt  = rr_ & 1;        // N tile (256 cols)
  const int mt  = (rr_ >> 1) & 3; // M tile (256 rows)
  const int bb  = rr_ >> 3;       // batch
  const int be  = bb * Edim + e;

  const int tid  = threadIdx.x;
  const int lane = tid & 63;
  const int wid  = tid >> 6;   // 0..7
  const int rw   = wid >> 2;   // 0..1: 64-row sub-block within the A half
  const int cw   = wid & 3;    // 0..3: 32-col sub-block within the B half

  // A staging (gathered DMA): per instr a wave covers 8 token rows; lane
  // loads swizzled k-chunk ((lane&7) ^ rsub) of row (base + rsub). LDS image
  // matches the panel layout exactly.
  const int rsub = lane >> 3;                 // 0..7, == row&7
  const int kcol = ((lane & 7) ^ rsub) * 8;   // pre-swizzled source chunk

  const unsigned short* pA[2][2];  // [half][instr]
#pragma unroll
  for (int h = 0; h < 2; ++h)
#pragma unroll
    for (int i = 0; i < 2; ++i) {
      const int rr  = h * 128 + wid * 16 + i * 8 + rsub;  // tile row 0..255
      const int tok = idx[be * Cdim + mt * 256 + rr];
      pA[h][i] = xbf + ((size_t)(bb * Tdim + tok)) * Ddim + kcol;
    }
  // B staging (contiguous DMA from panels)
  const unsigned short* Bbase = Wpan + ((size_t)(e * 2 + nt) * KT) * PAN;
  const int lo = lane * 8;  // lane's 16B within the wave's 1KB segment
  // drain idx loads so manual vmcnt counts below see exactly our stages
  asm volatile("s_waitcnt vmcnt(0)" ::: "memory");

#define STAGE_A_(h, dstArr, kt) do {                                         \
    async_copy16(pA[h][0] + (kt) * 64, &dstArr[wid * 16 * 64]);              \
    async_copy16(pA[h][1] + (kt) * 64, &dstArr[(wid * 16 + 8) * 64]);        \
  } while (0)
#define STAGE_B_(h, dstArr, kt) do {                                         \
    async_copy16(Bbase + (size_t)(kt) * PAN + ((h) * 128 + wid * 16) * 64 + lo, \
                 &dstArr[wid * 16 * 64]);                                    \
    async_copy16(Bbase + (size_t)(kt) * PAN + ((h) * 128 + wid * 16 + 8) * 64 + lo, \
                 &dstArr[(wid * 16 + 8) * 64]);                              \
  } while (0)

  // ---- prologue: 7 half-tiles = tile0 complete + A0,B0,B1 of tile1 ----
  STAGE_A_(0, sA_e0, 0);
  STAGE_B_(0, sB_e0, 0);
  STAGE_B_(1, sB_e1, 0);
  STAGE_A_(1, sA_e1, 0);
  STAGE_A_(0, sA_o0, 1);
  STAGE_B_(0, sB_o0, 1);
  STAGE_B_(1, sB_o1, 1);
  asm volatile("s_waitcnt vmcnt(6)" ::: "memory");  // tile0 (8 oldest) landed
  __builtin_amdgcn_s_barrier();
  FENCE();

  const int fr  = lane & 15;   // fragment m/n index
  const int fkc = lane >> 4;   // fragment k-chunk (0..3)
  const int sw  = fr & 7;      // read-side XOR (== row&7)

  f32x4 acc[2][2][4][2];
#pragma unroll
  for (int a = 0; a < 2; ++a)
#pragma unroll
    for (int bq = 0; bq < 2; ++bq)
#pragma unroll
      for (int im = 0; im < 4; ++im)
#pragma unroll
        for (int in = 0; in < 2; ++in)
          acc[a][bq][im][in] = (f32x4){0.f, 0.f, 0.f, 0.f};

  bf16x8 af[4][2], bf0[2][2], bf1[2][2];

#define LD_A(arr)                                                            \
  _Pragma("unroll")                                                          \
  for (int im = 0; im < 4; ++im)                                             \
    _Pragma("unroll")                                                        \
    for (int kk = 0; kk < 2; ++kk)                                           \
      af[im][kk] = *(const bf16x8*)&arr[(size_t)(rw * 64 + im * 16 + fr) * 64 \
                                        + (((kk * 4 + fkc) ^ sw) * 8)];
#define LD_B(arr, dst)                                                       \
  _Pragma("unroll")                                                          \
  for (int in = 0; in < 2; ++in)                                             \
    _Pragma("unroll")                                                        \
    for (int kk = 0; kk < 2; ++kk)                                           \
      dst[in][kk] = *(const bf16x8*)&arr[(size_t)(cw * 32 + in * 16 + fr) * 64 \
                                         + (((kk * 4 + fkc) ^ sw) * 8)];
#define MFMA16(aq, bq_, B_)                                                  \
  __builtin_amdgcn_s_setprio(1);                                             \
  _Pragma("unroll")                                                          \
  for (int im = 0; im < 4; ++im)                                             \
    _Pragma("unroll")                                                        \
    for (int in = 0; in < 2; ++in)                                           \
      _Pragma("unroll")                                                      \
      for (int kk = 0; kk < 2; ++kk)                                         \
        acc[aq][bq_][im][in] = __builtin_amdgcn_mfma_f32_16x16x32_bf16(      \
            af[im][kk], B_[in][kk], acc[aq][bq_][im][in], 0, 0, 0);          \
  __builtin_amdgcn_s_setprio(0);

  for (int it = 0; it < KT / 2; ++it) {
    const bool g2 = (it < 7);
    const int t1e = 2 * it + 1;  // even tile's t+1
    const int t2e = 2 * it + 2;  // even tile's t+2
    const int t2o = 2 * it + 3;  // odd tile's t+2

    // ================= even tile t = 2*it (slot E) =================
    // p0: quadrant (0,0)
    LD_A(sA_e0);
    LD_B(sB_e0, bf0);
    STAGE_A_(1, sA_o1, t1e);          // A1(t+1), always valid (t+1 <= 15)
    BAR();
    MFMA16(0, 0, bf0);
    BAR();
    // p1: quadrant (0,1)
    LD_B(sB_e1, bf1);
    if (g2) STAGE_A_(0, sA_e0, t2e);  // A0(t+2); reads of sA_e0 precede this
    BAR();
    MFMA16(0, 1, bf1);
    BAR();
    // p2: quadrant (1,1)
    LD_A(sA_e1);
    if (g2) STAGE_B_(0, sB_e0, t2e);
    BAR();
    MFMA16(1, 1, bf1);
    BAR();
    // p3: quadrant (1,0); tile-boundary counted wait
    if (g2) STAGE_B_(1, sB_e1, t2e);
    BAR();
    MFMA16(1, 0, bf0);
    if (it == 7) asm volatile("s_waitcnt vmcnt(0)" ::: "memory");
    else         asm volatile("s_waitcnt vmcnt(6)" ::: "memory");
    BAR();

    // ================= odd tile t = 2*it+1 (slot O) =================
    // p0: quadrant (0,0)
    LD_A(sA_o0);
    LD_B(sB_o0, bf0);
    if (g2) STAGE_A_(1, sA_e1, t2e);  // A1 of next even tile -> even slot
    BAR();
    MFMA16(0, 0, bf0);
    BAR();
    // p1: quadrant (0,1)
    LD_B(sB_o1, bf1);
    if (g2) STAGE_A_(0, sA_o0, t2o);  // A0(t+2)
    BAR();
    MFMA16(0, 1, bf1);
    BAR();
    // p2: quadrant (1,1)
    LD_A(sA_o1);
    if (g2) STAGE_B_(0, sB_o0, t2o);
    BAR();
    MFMA16(1, 1, bf1);
    BAR();
    // p3: quadrant (1,0); tile-boundary counted wait
    if (g2) STAGE_B_(1, sB_o1, t2o);
    BAR();
    MFMA16(1, 0, bf0);
    if (g2) asm volatile("s_waitcnt vmcnt(6)" ::: "memory");
    BAR();
  }
#undef STAGE_A_
#undef STAGE_B_
#undef LD_A
#undef LD_B
#undef MFMA16

  // Epilogue. C/D layout (verified m89/m91): col = lane&15, row = (lane>>4)*4 + reg.
  const int crow0 = (lane >> 4) * 4;
  float* outBase = out + (size_t)be * (Cdim * Odim)
                 + (size_t)(mt * 256) * Odim + nt * 256;
#pragma unroll
  for (int a = 0; a < 2; ++a)
#pragma unroll
    for (int im = 0; im < 4; ++im) {
      float* prow = outBase + (size_t)(a * 128 + rw * 64 + im * 16 + crow0) * Odim;
#pragma unroll
      for (int bq = 0; bq < 2; ++bq)
#pragma unroll
        for (int in = 0; in < 2; ++in) {
          const int col  = bq * 128 + cw * 32 + in * 16 + fr;
          const float bv = bias[e * Odim + nt * 256 + col];
          float* p = prow + col;
#pragma unroll
          for (int r4 = 0; r4 < 4; ++r4)
            p[(size_t)r4 * Odim] = acc[a][bq][im][in][r4] + bv;
        }
    }
}

extern "C" void kernel_launch(void* const* d_in, const int* in_sizes, int n_in,
                              void* d_out, int out_size, void* d_ws, size_t ws_size,
                              hipStream_t stream) {
  const float* x = (const float*)d_in[0];       // (B,T,D) f32
  const int* idx = (const int*)d_in[1];         // (B,E,C) i32
  const float* w = (const float*)d_in[2];       // (E,O,D) f32
  const float* bias = (const float*)d_in[3];    // (E,O) f32
  float* out = (float*)d_out;

  // Workspace: x_bf16 (32 MiB) then W panels (8 MiB)
  unsigned short* xbf = (unsigned short*)d_ws;
  unsigned short* Wp  = xbf + (size_t)Bdim * Tdim * Ddim;

  const int nx4  = Bdim * Tdim * Ddim / 4;            // 4,194,304
  const int nTot = nx4 + Edim * Odim * (Ddim / 8);    // + 524,288
  prep<<<(nTot + 255) / 256, 256, 0, stream>>>(x, w, xbf, Wp, nx4, nTot);

  // 32 (b,e) pairs x 4 M-tiles x 2 N-tiles = 256 blocks (1/CU), XCD-swizzled
  moe_mfma_gemm<<<256, 512, 0, stream>>>(xbf, Wp, idx, bias, out);
}